// Round 2
// baseline (540.401 us; speedup 1.0000x reference)
//
#include <hip/hip_runtime.h>

// out[b,i,j,d] = (table[x[b,i]] @ W1)[d] + (table[x[b,j]] @ W2)[d] + bias[d]
// VOCAB=8 -> only 64 distinct 128-float output rows. Precompute all 64
// combined rows C[vi][vj][:] (32 KB), then stream 536.9 MB of fp32 stores.
//
// R2 change: register-resident candidate rows. Each thread hoists its 8
// possible float4 values (Crow[0..7][dg]) into VGPRs and selects with a
// 3-level cndmask tree keyed on vj. Inner loop has ZERO LDS data reads
// (only the 4B vj broadcast), making the store stream structurally
// identical to the 6.2 TB/s fill kernel: register data + independent
// full-line coalesced stores.
// Purpose: last-standing H1 mechanism probe (per-store LDS dependence).
// If neutral, write_out is HBM-write-bound (~5.6 TB/s after subtracting
// the hidden output-poison fill) and we are at the roofline.

#define VOCAB 8
#define EMB   128
#define BATCH 4
#define LEN   512

typedef float v4f __attribute__((ext_vector_type(4)));

// ---------------------------------------------------------------------------
// Kernel A: 64 blocks, one per (vi,vj); 128 threads, one per output dim d.
// C[vi*8+vj][d] = sum_k table[vi,k]*W[k,d] + sum_k table[vj,k]*W[128+k,d] + b[d]
// ---------------------------------------------------------------------------
__global__ __launch_bounds__(128) void build_C(const float* __restrict__ table,
                                               const float* __restrict__ W,
                                               const float* __restrict__ bias,
                                               float* __restrict__ C) {
    const int vi = blockIdx.x >> 3;
    const int vj = blockIdx.x & 7;
    const int d  = threadIdx.x;

    __shared__ float t1[EMB];
    __shared__ float t2[EMB];
    t1[d] = table[vi * EMB + d];
    t2[d] = table[vj * EMB + d];
    __syncthreads();

    float s = bias[d];
    #pragma unroll 8
    for (int k = 0; k < EMB; ++k) {
        s += t1[k] * W[k * EMB + d];          // W1 = W[:128]
        s += t2[k] * W[(EMB + k) * EMB + d];  // W2 = W[128:]
    }
    C[(size_t)blockIdx.x * EMB + d] = s;
}

// ---------------------------------------------------------------------------
// Kernel B: one block per (b,i). Thread t: dg = t&31 (which 16B chunk of the
// 512B row), js = t>>5 (8 j's per iteration). Wave writes 1 KB contiguous.
// The 8 candidate float4 values for this thread live in c0..c7 (VGPRs);
// per-store data = 28-cndmask select on vj (3-bit). ~12 us of VALU per SIMD
// aggregate -- far under the 86 us store-stream floor, so free if hidden.
// ---------------------------------------------------------------------------
__global__ __launch_bounds__(256) void write_out(const int* __restrict__ x,
                                                 const float* __restrict__ C,
                                                 float* __restrict__ out) {
    const int bi = blockIdx.x;        // 0..2047
    const int b  = bi >> 9;
    const int i  = bi & 511;
    const int t  = threadIdx.x;
    const int dg = t & 31;
    const int js = t >> 5;

    __shared__ int xrow[LEN];              // 2 KB (only LDS left)

    const int* xb = x + b * LEN;
    for (int j = t; j < LEN; j += 256) xrow[j] = xb[j];

    const int vi = xb[i];             // uniform across block

    // 8 candidate float4 values for this thread's dg, into registers.
    // Per 32-group these are 512B contiguous reads; C is 32 KB, L2/L3-hot.
    const v4f* Cv = (const v4f*)(C + (size_t)vi * VOCAB * EMB);
    const v4f c0 = Cv[0 * 32 + dg];
    const v4f c1 = Cv[1 * 32 + dg];
    const v4f c2 = Cv[2 * 32 + dg];
    const v4f c3 = Cv[3 * 32 + dg];
    const v4f c4 = Cv[4 * 32 + dg];
    const v4f c5 = Cv[5 * 32 + dg];
    const v4f c6 = Cv[6 * 32 + dg];
    const v4f c7 = Cv[7 * 32 + dg];
    __syncthreads();

    v4f* orow = (v4f*)out + (size_t)bi * LEN * (EMB / 4);

    #pragma unroll 8
    for (int j0 = 0; j0 < LEN; j0 += 8) {
        const int j  = j0 + js;
        const int vj = xrow[j];                       // 4B broadcast per 32-group
        const bool b0 = vj & 1;
        const bool b1 = vj & 2;
        const bool b2 = vj & 4;
        const v4f t01 = b0 ? c1 : c0;
        const v4f t23 = b0 ? c3 : c2;
        const v4f t45 = b0 ? c5 : c4;
        const v4f t67 = b0 ? c7 : c6;
        const v4f u0  = b1 ? t23 : t01;
        const v4f u1  = b1 ? t67 : t45;
        const v4f w   = b2 ? u1  : u0;
        orow[(size_t)j * (EMB / 4) + dg] = w;
    }
}

extern "C" void kernel_launch(void* const* d_in, const int* in_sizes, int n_in,
                              void* d_out, int out_size, void* d_ws, size_t ws_size,
                              hipStream_t stream) {
    const int*   x     = (const int*)d_in[0];     // (4,512) int32
    const float* table = (const float*)d_in[1];   // (8,128) f32
    const float* W     = (const float*)d_in[2];   // (256,128) f32
    const float* bias  = (const float*)d_in[3];   // (128,) f32
    float*       out   = (float*)d_out;           // (4,512,512,128) f32
    float*       C     = (float*)d_ws;            // 32 KB scratch

    build_C<<<VOCAB * VOCAB, 128, 0, stream>>>(table, W, bias, C);
    write_out<<<BATCH * LEN, 256, 0, stream>>>(x, C, out);
}